// Round 6
// baseline (437.229 us; speedup 1.0000x reference)
//
#include <hip/hip_runtime.h>
#include <math.h>

#define N_NODES 8192
#define F_DIM   2048
#define E_EDGES 262144
#define H1      32
#define H2      16
#define ALPHA_C 0.9f

typedef float f4v __attribute__((ext_vector_type(4)));

// ---------------------------------------------------------------------------
// GEMM tile body (proven round-0 config): BM=128, BN=32, BK=32, 256 thr,
// TM=4, TN=4. One call computes 128 rows x 128 K-depth for K-slice `kslice`.
// atomicAdd-accumulates into zeroed xw (split-K order-independent).
__device__ __forceinline__ void gemm_tile(const float* __restrict__ feat,
                                          const float* __restrict__ W0,
                                          float* __restrict__ xw,
                                          float (*As)[36], float (*Bt)[36],
                                          int rb, int kslice) {
    const int r0 = rb * 128;
    const int kbase = kslice * 128;
    const int t = threadIdx.x;
    const int ct = t & 7;    // 8 col-threads  (cols ct + 8j)
    const int rt = t >> 3;   // 32 row-threads (rows rt + 32m)
    float acc[4][4] = {};
    for (int kb = 0; kb < 128; kb += 32) {
        const int koff = kbase + kb;
        __syncthreads();
#pragma unroll
        for (int p = 0; p < 4; p++) {
            int f = t + p * 256;
            int row = f >> 3, q = f & 7;
            float4 v = *(const float4*)&feat[(size_t)(r0 + row) * F_DIM + koff + q * 4];
            *(float4*)&As[row][q * 4] = v;
        }
        {
            int k = t >> 3, q = t & 7;
            float4 v = *(const float4*)&W0[(size_t)(koff + k) * H1 + q * 4];
            Bt[q * 4 + 0][k] = v.x; Bt[q * 4 + 1][k] = v.y;
            Bt[q * 4 + 2][k] = v.z; Bt[q * 4 + 3][k] = v.w;
        }
        __syncthreads();
#pragma unroll
        for (int k4 = 0; k4 < 8; k4++) {
            float4 a[4], bb[4];
#pragma unroll
            for (int m = 0; m < 4; m++) a[m] = *(const float4*)&As[rt + 32 * m][k4 * 4];
#pragma unroll
            for (int j = 0; j < 4; j++) bb[j] = *(const float4*)&Bt[ct + 8 * j][k4 * 4];
#pragma unroll
            for (int m = 0; m < 4; m++)
#pragma unroll
                for (int j = 0; j < 4; j++)
                    acc[m][j] += a[m].x * bb[j].x + a[m].y * bb[j].y +
                                 a[m].z * bb[j].z + a[m].w * bb[j].w;
        }
    }
#pragma unroll
    for (int m = 0; m < 4; m++)
#pragma unroll
        for (int j = 0; j < 4; j++)
            atomicAdd(&xw[(size_t)(r0 + rt + 32 * m) * H1 + ct + 8 * j], acc[m][j]);
}

// ---------------------------------------------------------------------------
// F1: blocks [0,1024) = degree histogram; [1024,1536) = GEMM K-slices 0-7.
__global__ __launch_bounds__(256) void k_f1(const float* __restrict__ feat,
                                            const float* __restrict__ W0,
                                            float* __restrict__ xw,
                                            const int* __restrict__ dst,
                                            int* __restrict__ deg) {
    __shared__ float As[128][36];
    __shared__ float Bt[32][36];
    const int b = blockIdx.x;
    if (b < 1024) {
        int e = b * 256 + threadIdx.x;
        if (e < E_EDGES) atomicAdd(&deg[dst[e]], 1);
        return;
    }
    const int bp = b - 1024;              // [0,512)
    gemm_tile(feat, W0, xw, As, Bt, bp >> 3, bp & 7);
}

// ---------------------------------------------------------------------------
// F2: block 0 = prefix scan (256 thr, 32 elems/thr); blocks [1,257) =
// GEMM K-slices 8-11. Scan overlaps GEMM instead of idling 255 CUs.
__global__ __launch_bounds__(256) void k_f2(const float* __restrict__ feat,
                                            const float* __restrict__ W0,
                                            float* __restrict__ xw,
                                            const int* __restrict__ deg,
                                            int* __restrict__ rowptr,
                                            int* __restrict__ cursor,
                                            float* __restrict__ norm) {
    __shared__ float As[128][36];
    __shared__ float Bt[32][36];
    const int b = blockIdx.x;
    if (b > 0) {
        const int bp = b - 1;             // [0,256)
        gemm_tile(feat, W0, xw, As, Bt, bp >> 2, 8 + (bp & 3));
        return;
    }
    // ---- scan path: 256 threads, 32 elems each ----
    __shared__ int wsum[4];
    int t = threadIdx.x;                  // 0..255
    int base = t * 32;
    int local[32];
    int s = 0;
#pragma unroll
    for (int i = 0; i < 32; i++) { local[i] = s; s += deg[base + i]; }
    int lane = t & 63, wv = t >> 6;       // 4 waves
    int incl = s;
#pragma unroll
    for (int off = 1; off < 64; off <<= 1) {
        int u = __shfl_up(incl, off);
        if (lane >= off) incl += u;
    }
    if (lane == 63) wsum[wv] = incl;
    __syncthreads();
    if (t == 0) {
        int a = wsum[0];
#pragma unroll
        for (int i = 1; i < 4; i++) { a += wsum[i]; wsum[i] = a; }
    }
    __syncthreads();
    int waveoff = (wv == 0) ? 0 : wsum[wv - 1];
    int excl = waveoff + incl - s;        // exclusive offset for this thread
#pragma unroll
    for (int i = 0; i < 32; i++) {
        int r = excl + local[i];
        rowptr[base + i] = r;
        cursor[base + i] = r;
        int d = ((i == 31) ? s : local[i + 1]) - local[i];
        norm[base + i] = rsqrtf((float)(d > 0 ? d : 1));
    }
    if (t == 0) rowptr[N_NODES] = wsum[3];
}

// ---------------------------------------------------------------------------
// F3: blocks [0,1024) = CSR scatter; [1024,1280) = GEMM K-slices 12-15.
__global__ __launch_bounds__(256) void k_f3(const float* __restrict__ feat,
                                            const float* __restrict__ W0,
                                            float* __restrict__ xw,
                                            const int* __restrict__ src,
                                            const int* __restrict__ dst,
                                            int* __restrict__ cursor,
                                            int* __restrict__ csr_src) {
    __shared__ float As[128][36];
    __shared__ float Bt[32][36];
    const int b = blockIdx.x;
    if (b < 1024) {
        int e = b * 256 + threadIdx.x;
        if (e < E_EDGES) {
            int d = dst[e];
            int p = atomicAdd(&cursor[d], 1);
            csr_src[p] = src[e];
        }
        return;
    }
    const int bp = b - 1024;              // [0,256)
    gemm_tile(feat, W0, xw, As, Bt, bp >> 2, 12 + (bp & 3));
}

// ---------------------------------------------------------------------------
// K4 (fused): first graph conv aggregate + gate dots (proven round 4).
__global__ __launch_bounds__(256) void k_agg1(const int* __restrict__ rowptr,
                                              const int* __restrict__ csr_src,
                                              const float* __restrict__ xw,
                                              const float* __restrict__ norm,
                                              const float* __restrict__ gw,
                                              float* __restrict__ h,
                                              float* __restrict__ dd,
                                              float* __restrict__ ds) {
    int wid = (blockIdx.x * blockDim.x + threadIdx.x) >> 6;  // node id (wave-uniform)
    int lane = threadIdx.x & 63;
    int col = lane & 31, half = lane >> 5;
    int beg = rowptr[wid], end = rowptr[wid + 1];
    float acc = 0.0f;
    for (int p = beg + half; p < end; p += 2) {
        int s = csr_src[p];
        acc += norm[s] * xw[(size_t)s * H1 + col];
    }
    acc += __shfl_xor(acc, 32, 64);          // both halves hold col total
    float hv = fmaxf(norm[wid] * acc, 0.0f); // valid on all 64 lanes
    if (half == 0) h[(size_t)wid * H1 + col] = hv;
    float c0 = hv * gw[col];
    float c1 = hv * gw[H1 + col];
#pragma unroll
    for (int off = 1; off < 32; off <<= 1) {
        c0 += __shfl_xor(c0, off);
        c1 += __shfl_xor(c1, off);
    }
    if (lane == 0) { dd[wid] = c0; ds[wid] = c1; }
}

// ---------------------------------------------------------------------------
// K5 (fused): edge-gated aggregation + mean + logstd + reparameterize
// (proven round 4: mean reuses the z_auto h-gather by linearity).
__global__ __launch_bounds__(256) void k_agg2z(const int* __restrict__ rowptr,
                                               const int* __restrict__ csr_src,
                                               const float* __restrict__ h,
                                               const float* __restrict__ dd,
                                               const float* __restrict__ ds,
                                               const float* __restrict__ norm,
                                               const float* __restrict__ gb,
                                               const float* __restrict__ t2,
                                               const float* __restrict__ Wm,
                                               const float* __restrict__ noise,
                                               float* __restrict__ z) {
    __shared__ float shT[4][H1];  // t-vector row per wave (wave-private)
    __shared__ float shH[4][H1];  // norm_n * sum norm_s h[s] row per wave
    int wid = (blockIdx.x * blockDim.x + threadIdx.x) >> 6;  // node id
    int w = (threadIdx.x >> 6) & 3;                          // wave in block
    int lane = threadIdx.x & 63;
    int col = lane & 31, half = lane >> 5;
    int beg = rowptr[wid], end = rowptr[wid + 1];
    float dd_n = dd[wid];
    float norm_n = norm[wid];
    float gb0 = gb[0];
    float accz = 0.0f, acch = 0.0f;
    for (int p = beg + half; p < end; p += 2) {
        int s = csr_src[p];
        float ns = norm[s];
        float x = fminf(dd_n + ds[s] + gb0, 15.0f);
        float e2 = __expf(2.0f * x);
        float th = __fdividef(e2 - 1.0f, e2 + 1.0f);
        float hv = h[(size_t)s * H1 + col];    // single gather feeds BOTH sums
        accz += th * ns * hv;
        acch += ns * hv;
    }
    accz += __shfl_xor(accz, 32);
    acch += __shfl_xor(acch, 32);
    if (half == 0) {
        shT[w][col] = accz * (norm_n * ALPHA_C) + ALPHA_C * h[(size_t)wid * H1 + col];
        shH[w][col] = acch * norm_n;           // mean = shH @ Wm
    }
    // no __syncthreads(): same-wave DS write->read is ordered (HW-proven)
    if (lane < 16) {
        int k = lane;
        float ls = 0.0f, mn = 0.0f;
#pragma unroll
        for (int c = 0; c < H1; c++) {
            ls += shT[w][c] * t2[c * H2 + k];
            mn += shH[w][c] * Wm[c * H2 + k];
        }
        size_t zi = (size_t)wid * H2 + k;
        z[zi] = noise[zi] * __expf(ls) + mn;
    }
}

// ---------------------------------------------------------------------------
// K6: out = sigmoid(z @ z^T), 128x128 tile per block, 8x8 per thread.
__global__ __launch_bounds__(256) void k_outer(const float* __restrict__ z,
                                               float* __restrict__ out) {
    __shared__ float Zr[H2][128];
    __shared__ float Zc[H2][128];
    const int bx = blockIdx.x, by = blockIdx.y;
    const int t = threadIdx.x;
#pragma unroll
    for (int p = 0; p < 2; p++) {
        int fi = t + p * 256;
        int row = fi >> 2, q = fi & 3;
        float4 v = *(const float4*)&z[(size_t)(by * 128 + row) * H2 + q * 4];
        Zr[q * 4 + 0][row] = v.x; Zr[q * 4 + 1][row] = v.y;
        Zr[q * 4 + 2][row] = v.z; Zr[q * 4 + 3][row] = v.w;
        float4 w = *(const float4*)&z[(size_t)(bx * 128 + row) * H2 + q * 4];
        Zc[q * 4 + 0][row] = w.x; Zc[q * 4 + 1][row] = w.y;
        Zc[q * 4 + 2][row] = w.z; Zc[q * 4 + 3][row] = w.w;
    }
    __syncthreads();
    const int tx = t & 15, ty = t >> 4;
    float acc[8][8] = {};
#pragma unroll
    for (int k = 0; k < H2; k++) {
        float a[8], b[8];
        *(float4*)&a[0] = *(const float4*)&Zr[k][ty * 4];
        *(float4*)&a[4] = *(const float4*)&Zr[k][64 + ty * 4];
        *(float4*)&b[0] = *(const float4*)&Zc[k][tx * 4];
        *(float4*)&b[4] = *(const float4*)&Zc[k][64 + tx * 4];
#pragma unroll
        for (int i = 0; i < 8; i++)
#pragma unroll
            for (int j = 0; j < 8; j++) acc[i][j] += a[i] * b[j];
    }
#pragma unroll
    for (int i = 0; i < 8; i++) {
        size_t row = (size_t)by * 128 + ((i < 4) ? (ty * 4 + i) : (64 + ty * 4 + i - 4));
        f4v o0, o1;
        o0.x = 1.0f / (1.0f + __expf(-acc[i][0]));
        o0.y = 1.0f / (1.0f + __expf(-acc[i][1]));
        o0.z = 1.0f / (1.0f + __expf(-acc[i][2]));
        o0.w = 1.0f / (1.0f + __expf(-acc[i][3]));
        o1.x = 1.0f / (1.0f + __expf(-acc[i][4]));
        o1.y = 1.0f / (1.0f + __expf(-acc[i][5]));
        o1.z = 1.0f / (1.0f + __expf(-acc[i][6]));
        o1.w = 1.0f / (1.0f + __expf(-acc[i][7]));
        __builtin_nontemporal_store(o0, (f4v*)&out[row * N_NODES + bx * 128 + tx * 4]);
        __builtin_nontemporal_store(o1, (f4v*)&out[row * N_NODES + bx * 128 + 64 + tx * 4]);
    }
}

// ---------------------------------------------------------------------------
extern "C" void kernel_launch(void* const* d_in, const int* in_sizes, int n_in,
                              void* d_out, int out_size, void* d_ws, size_t ws_size,
                              hipStream_t stream) {
    const float* feat  = (const float*)d_in[0];
    const float* W0    = (const float*)d_in[1];
    const float* Wm    = (const float*)d_in[2];
    const float* gw    = (const float*)d_in[3];
    const float* gb    = (const float*)d_in[4];
    const float* t2    = (const float*)d_in[5];
    const float* noise = (const float*)d_in[6];
    const int*   src   = (const int*)d_in[7];
    const int*   dst   = (const int*)d_in[8];
    float* out = (float*)d_out;

    char* w = (char*)d_ws;
    size_t off = 0;
    auto alloc = [&](size_t bytes) {
        void* p = w + off;
        off = (off + bytes + 255) & ~(size_t)255;
        return p;
    };
    // deg and xw first + contiguous -> single zeroing memset
    int*   deg     = (int*)alloc(N_NODES * 4);
    float* xw      = (float*)alloc((size_t)N_NODES * H1 * 4);
    size_t zero_bytes = off;
    int*   rowptr  = (int*)alloc((N_NODES + 1) * 4);
    int*   cursor  = (int*)alloc(N_NODES * 4);
    int*   csr_src = (int*)alloc(E_EDGES * 4);
    float* norm    = (float*)alloc(N_NODES * 4);
    float* h       = (float*)alloc((size_t)N_NODES * H1 * 4);
    float* dd      = (float*)alloc(N_NODES * 4);
    float* ds      = (float*)alloc(N_NODES * 4);
    float* z       = (float*)alloc((size_t)N_NODES * H2 * 4);

    (void)hipMemsetAsync(deg, 0, zero_bytes, stream);

    // GEMM pipelined across the CSR chain: each stage carries a K-chunk.
    k_f1<<<1536, 256, 0, stream>>>(feat, W0, xw, dst, deg);            // deg || K 0-7
    k_f2<<<257, 256, 0, stream>>>(feat, W0, xw, deg, rowptr, cursor, norm); // scan || K 8-11
    k_f3<<<1280, 256, 0, stream>>>(feat, W0, xw, src, dst, cursor, csr_src); // scatter || K 12-15
    k_agg1<<<N_NODES / 4, 256, 0, stream>>>(rowptr, csr_src, xw, norm, gw, h, dd, ds);
    k_agg2z<<<N_NODES / 4, 256, 0, stream>>>(rowptr, csr_src, h, dd, ds, norm,
                                             gb, t2, Wm, noise, z);
    k_outer<<<dim3(N_NODES / 128, N_NODES / 128), 256, 0, stream>>>(z, out);
}

// Round 7
// 423.329 us; speedup vs baseline: 1.0328x; 1.0328x over previous
//
#include <hip/hip_runtime.h>
#include <math.h>

#define N_NODES 8192
#define F_DIM   2048
#define E_EDGES 262144
#define H1      32
#define H2      16
#define ALPHA_C 0.9f

typedef float f4v __attribute__((ext_vector_type(4)));

// ---------------------------------------------------------------------------
// K1 (fused): blocks [0,1024) = GEMM xw = feat @ W0; blocks [1024,2048) =
// in-degree histogram. Independent work overlapped (proven rounds 3-4).
// GEMM: BM=128, BN=32, BK=32, 256 thr, TM=4, TN=4, split-K=16 (full
// occupancy; round-6 chunked variant at 1 blk/CU regressed — keep whole).
__global__ __launch_bounds__(256) void k_gemm_deg(const float* __restrict__ feat,
                                                  const float* __restrict__ W0,
                                                  float* __restrict__ xw,
                                                  const int* __restrict__ dst,
                                                  int* __restrict__ deg) {
    __shared__ float As[128][36];
    __shared__ float Bt[32][36];
    const int b = blockIdx.x;
    if (b >= 1024) {
        // ---- degree histogram path ----
        int e = (b - 1024) * 256 + threadIdx.x;
        if (e < E_EDGES) atomicAdd(&deg[dst[e]], 1);
        return;
    }
    // ---- GEMM path ----
    const int r0 = (b >> 4) * 128;        // 64 row-blocks
    const int kbase = (b & 15) * 128;     // 16 K-slices
    const int t = threadIdx.x;
    const int ct = t & 7;    // 8 col-threads  (cols ct + 8j)
    const int rt = t >> 3;   // 32 row-threads (rows rt + 32m)
    float acc[4][4] = {};
    for (int kb = 0; kb < 128; kb += 32) {
        const int koff = kbase + kb;
        __syncthreads();
#pragma unroll
        for (int p = 0; p < 4; p++) {
            int f = t + p * 256;
            int row = f >> 3, q = f & 7;
            float4 v = *(const float4*)&feat[(size_t)(r0 + row) * F_DIM + koff + q * 4];
            *(float4*)&As[row][q * 4] = v;
        }
        {
            int k = t >> 3, q = t & 7;
            float4 v = *(const float4*)&W0[(size_t)(koff + k) * H1 + q * 4];
            Bt[q * 4 + 0][k] = v.x; Bt[q * 4 + 1][k] = v.y;
            Bt[q * 4 + 2][k] = v.z; Bt[q * 4 + 3][k] = v.w;
        }
        __syncthreads();
#pragma unroll
        for (int k4 = 0; k4 < 8; k4++) {
            float4 a[4], bb[4];
#pragma unroll
            for (int m = 0; m < 4; m++) a[m] = *(const float4*)&As[rt + 32 * m][k4 * 4];
#pragma unroll
            for (int j = 0; j < 4; j++) bb[j] = *(const float4*)&Bt[ct + 8 * j][k4 * 4];
#pragma unroll
            for (int m = 0; m < 4; m++)
#pragma unroll
                for (int j = 0; j < 4; j++)
                    acc[m][j] += a[m].x * bb[j].x + a[m].y * bb[j].y +
                                 a[m].z * bb[j].z + a[m].w * bb[j].w;
        }
    }
#pragma unroll
    for (int m = 0; m < 4; m++)
#pragma unroll
        for (int j = 0; j < 4; j++)
            atomicAdd(&xw[(size_t)(r0 + rt + 32 * m) * H1 + ct + 8 * j], acc[m][j]);
}

// ---------------------------------------------------------------------------
// K2: exclusive prefix scan of deg -> rowptr, cursor; norm = rsqrt(max(deg,1))
// shuffle-based scan (proven rounds 2-4).
__global__ void k_scan(const int* __restrict__ deg, int* __restrict__ rowptr,
                       int* __restrict__ cursor, float* __restrict__ norm) {
    __shared__ int wsum[16];
    int t = threadIdx.x;          // 0..1023
    int base = t * 8;
    int local[8];
    int s = 0;
#pragma unroll
    for (int i = 0; i < 8; i++) { local[i] = s; s += deg[base + i]; }
    int lane = t & 63, wv = t >> 6;
    int incl = s;
#pragma unroll
    for (int off = 1; off < 64; off <<= 1) {
        int u = __shfl_up(incl, off);
        if (lane >= off) incl += u;
    }
    if (lane == 63) wsum[wv] = incl;
    __syncthreads();
    if (t < 16) {
        int x = wsum[t];
#pragma unroll
        for (int off = 1; off < 16; off <<= 1) {
            int u = __shfl_up(x, off);
            if (t >= off) x += u;
        }
        wsum[t] = x;   // inclusive scan of the 16 wave sums
    }
    __syncthreads();
    int waveoff = (wv == 0) ? 0 : wsum[wv - 1];
    int excl = waveoff + incl - s;   // exclusive offset for this thread's 8 elems
#pragma unroll
    for (int i = 0; i < 8; i++) {
        int r = excl + local[i];
        rowptr[base + i] = r;
        cursor[base + i] = r;
        int d = ((i == 7) ? s : local[i + 1]) - local[i];
        norm[base + i] = rsqrtf((float)(d > 0 ? d : 1));
    }
    if (t == 1023) rowptr[N_NODES] = waveoff + incl;
}

// ---------------------------------------------------------------------------
// K3: scatter edges into CSR (counting sort; order within segment irrelevant)
__global__ void k_scatter(const int* __restrict__ src, const int* __restrict__ dst,
                          int* __restrict__ cursor, int* __restrict__ csr_src) {
    int e = blockIdx.x * 256 + threadIdx.x;
    if (e < E_EDGES) {
        int d = dst[e];
        int p = atomicAdd(&cursor[d], 1);
        csr_src[p] = src[e];
    }
}

// ---------------------------------------------------------------------------
// K4 (fused): first graph conv aggregate + gate dots (proven round 4).
__global__ __launch_bounds__(256) void k_agg1(const int* __restrict__ rowptr,
                                              const int* __restrict__ csr_src,
                                              const float* __restrict__ xw,
                                              const float* __restrict__ norm,
                                              const float* __restrict__ gw,
                                              float* __restrict__ h,
                                              float* __restrict__ dd,
                                              float* __restrict__ ds) {
    int wid = (blockIdx.x * blockDim.x + threadIdx.x) >> 6;  // node id (wave-uniform)
    int lane = threadIdx.x & 63;
    int col = lane & 31, half = lane >> 5;
    int beg = rowptr[wid], end = rowptr[wid + 1];
    float acc = 0.0f;
    for (int p = beg + half; p < end; p += 2) {
        int s = csr_src[p];
        acc += norm[s] * xw[(size_t)s * H1 + col];
    }
    acc += __shfl_xor(acc, 32, 64);          // both halves hold col total
    float hv = fmaxf(norm[wid] * acc, 0.0f); // valid on all 64 lanes
    if (half == 0) h[(size_t)wid * H1 + col] = hv;
    float c0 = hv * gw[col];
    float c1 = hv * gw[H1 + col];
#pragma unroll
    for (int off = 1; off < 32; off <<= 1) {
        c0 += __shfl_xor(c0, off);
        c1 += __shfl_xor(c1, off);
    }
    if (lane == 0) { dd[wid] = c0; ds[wid] = c1; }
}

// ---------------------------------------------------------------------------
// K5 (fused): edge-gated aggregation + mean + logstd + reparameterize
// (proven round 4: mean reuses the z_auto h-gather by linearity).
__global__ __launch_bounds__(256) void k_agg2z(const int* __restrict__ rowptr,
                                               const int* __restrict__ csr_src,
                                               const float* __restrict__ h,
                                               const float* __restrict__ dd,
                                               const float* __restrict__ ds,
                                               const float* __restrict__ norm,
                                               const float* __restrict__ gb,
                                               const float* __restrict__ t2,
                                               const float* __restrict__ Wm,
                                               const float* __restrict__ noise,
                                               float* __restrict__ z) {
    __shared__ float shT[4][H1];  // t-vector row per wave (wave-private)
    __shared__ float shH[4][H1];  // norm_n * sum norm_s h[s] row per wave
    int wid = (blockIdx.x * blockDim.x + threadIdx.x) >> 6;  // node id
    int w = (threadIdx.x >> 6) & 3;                          // wave in block
    int lane = threadIdx.x & 63;
    int col = lane & 31, half = lane >> 5;
    int beg = rowptr[wid], end = rowptr[wid + 1];
    float dd_n = dd[wid];
    float norm_n = norm[wid];
    float gb0 = gb[0];
    float accz = 0.0f, acch = 0.0f;
    for (int p = beg + half; p < end; p += 2) {
        int s = csr_src[p];
        float ns = norm[s];
        float x = fminf(dd_n + ds[s] + gb0, 15.0f);
        float e2 = __expf(2.0f * x);
        float th = __fdividef(e2 - 1.0f, e2 + 1.0f);
        float hv = h[(size_t)s * H1 + col];    // single gather feeds BOTH sums
        accz += th * ns * hv;
        acch += ns * hv;
    }
    accz += __shfl_xor(accz, 32);
    acch += __shfl_xor(acch, 32);
    if (half == 0) {
        shT[w][col] = accz * (norm_n * ALPHA_C) + ALPHA_C * h[(size_t)wid * H1 + col];
        shH[w][col] = acch * norm_n;           // mean = shH @ Wm
    }
    // no __syncthreads(): same-wave DS write->read is ordered (HW-proven)
    if (lane < 16) {
        int k = lane;
        float ls = 0.0f, mn = 0.0f;
#pragma unroll
        for (int c = 0; c < H1; c++) {
            ls += shT[w][c] * t2[c * H2 + k];
            mn += shH[w][c] * Wm[c * H2 + k];
        }
        size_t zi = (size_t)wid * H2 + k;
        z[zi] = noise[zi] * __expf(ls) + mn;
    }
}

// ---------------------------------------------------------------------------
// K6: out = sigmoid(z @ z^T) exploiting symmetry: only upper-triangle blocks
// (bx <= by) compute; sigmoid applied once; mirror tile (bx,by) emitted via
// LDS transpose in two 64-col halves. Mirror values are BITWISE identical
// (same k-order products, a*b==b*a) -> absmax unchanged. All barriers are
// block-uniform (bx,by same for the whole block).
__global__ __launch_bounds__(256) void k_outer(const float* __restrict__ z,
                                               float* __restrict__ out) {
    __shared__ float Zr[H2][128];
    __shared__ float Zc[H2][128];
    __shared__ float Lt[64][132];   // transposed half-tile: [col][row], padded
    const int bx = blockIdx.x, by = blockIdx.y;
    if (bx > by) return;            // lower triangle: produced by mirror
    const int t = threadIdx.x;
#pragma unroll
    for (int p = 0; p < 2; p++) {
        int fi = t + p * 256;
        int row = fi >> 2, q = fi & 3;
        float4 v = *(const float4*)&z[(size_t)(by * 128 + row) * H2 + q * 4];
        Zr[q * 4 + 0][row] = v.x; Zr[q * 4 + 1][row] = v.y;
        Zr[q * 4 + 2][row] = v.z; Zr[q * 4 + 3][row] = v.w;
        float4 w = *(const float4*)&z[(size_t)(bx * 128 + row) * H2 + q * 4];
        Zc[q * 4 + 0][row] = w.x; Zc[q * 4 + 1][row] = w.y;
        Zc[q * 4 + 2][row] = w.z; Zc[q * 4 + 3][row] = w.w;
    }
    __syncthreads();
    const int tx = t & 15, ty = t >> 4;
    float acc[8][8] = {};
#pragma unroll
    for (int k = 0; k < H2; k++) {
        float a[8], b[8];
        *(float4*)&a[0] = *(const float4*)&Zr[k][ty * 4];
        *(float4*)&a[4] = *(const float4*)&Zr[k][64 + ty * 4];
        *(float4*)&b[0] = *(const float4*)&Zc[k][tx * 4];
        *(float4*)&b[4] = *(const float4*)&Zc[k][64 + tx * 4];
#pragma unroll
        for (int i = 0; i < 8; i++)
#pragma unroll
            for (int j = 0; j < 8; j++) acc[i][j] += a[i] * b[j];
    }
    // sigmoid once, in place; direct store of tile (by,bx)
#pragma unroll
    for (int i = 0; i < 8; i++) {
#pragma unroll
        for (int j = 0; j < 8; j++) acc[i][j] = 1.0f / (1.0f + __expf(-acc[i][j]));
        size_t row = (size_t)by * 128 + ((i < 4) ? (ty * 4 + i) : (64 + ty * 4 + i - 4));
        f4v o0, o1;
        o0.x = acc[i][0]; o0.y = acc[i][1]; o0.z = acc[i][2]; o0.w = acc[i][3];
        o1.x = acc[i][4]; o1.y = acc[i][5]; o1.z = acc[i][6]; o1.w = acc[i][7];
        __builtin_nontemporal_store(o0, (f4v*)&out[row * N_NODES + bx * 128 + tx * 4]);
        __builtin_nontemporal_store(o1, (f4v*)&out[row * N_NODES + bx * 128 + 64 + tx * 4]);
    }
    if (bx == by) return;           // diagonal: no mirror needed
    // mirror tile (bx,by) via LDS transpose, two 64-col halves
#pragma unroll
    for (int hh = 0; hh < 2; hh++) {
        __syncthreads();            // Lt reuse boundary (block-uniform)
#pragma unroll
        for (int i = 0; i < 8; i++) {
            int r = (i < 4) ? (ty * 4 + i) : (64 + ty * 4 + i - 4);
#pragma unroll
            for (int jj = 0; jj < 4; jj++)
                Lt[tx * 4 + jj][r] = acc[i][hh * 4 + jj];  // col-local, row
        }
        __syncthreads();
        // coalesced read+store: 64 rows x 128 cols = 2048 float4
#pragma unroll
        for (int p = 0; p < 8; p++) {
            int fi = t + p * 256;
            int cl = fi >> 5, q = fi & 31;   // cl: mirror-row-local, q*4: col
            float4 v = *(const float4*)&Lt[cl][q * 4];
            size_t row = (size_t)bx * 128 + hh * 64 + cl;
            __builtin_nontemporal_store(*(f4v*)&v,
                (f4v*)&out[row * N_NODES + by * 128 + q * 4]);
        }
    }
}

// ---------------------------------------------------------------------------
extern "C" void kernel_launch(void* const* d_in, const int* in_sizes, int n_in,
                              void* d_out, int out_size, void* d_ws, size_t ws_size,
                              hipStream_t stream) {
    const float* feat  = (const float*)d_in[0];
    const float* W0    = (const float*)d_in[1];
    const float* Wm    = (const float*)d_in[2];
    const float* gw    = (const float*)d_in[3];
    const float* gb    = (const float*)d_in[4];
    const float* t2    = (const float*)d_in[5];
    const float* noise = (const float*)d_in[6];
    const int*   src   = (const int*)d_in[7];
    const int*   dst   = (const int*)d_in[8];
    float* out = (float*)d_out;

    char* w = (char*)d_ws;
    size_t off = 0;
    auto alloc = [&](size_t bytes) {
        void* p = w + off;
        off = (off + bytes + 255) & ~(size_t)255;
        return p;
    };
    // deg and xw first + contiguous -> single zeroing memset
    int*   deg     = (int*)alloc(N_NODES * 4);
    float* xw      = (float*)alloc((size_t)N_NODES * H1 * 4);
    size_t zero_bytes = off;
    int*   rowptr  = (int*)alloc((N_NODES + 1) * 4);
    int*   cursor  = (int*)alloc(N_NODES * 4);
    int*   csr_src = (int*)alloc(E_EDGES * 4);
    float* norm    = (float*)alloc(N_NODES * 4);
    float* h       = (float*)alloc((size_t)N_NODES * H1 * 4);
    float* dd      = (float*)alloc(N_NODES * 4);
    float* ds      = (float*)alloc(N_NODES * 4);
    float* z       = (float*)alloc((size_t)N_NODES * H2 * 4);

    (void)hipMemsetAsync(deg, 0, zero_bytes, stream);

    // GEMM blocks [0,1024) + degree blocks [1024,2048) run concurrently
    k_gemm_deg<<<2048, 256, 0, stream>>>(feat, W0, xw, dst, deg);
    k_scan<<<1, 1024, 0, stream>>>(deg, rowptr, cursor, norm);
    k_scatter<<<E_EDGES / 256, 256, 0, stream>>>(src, dst, cursor, csr_src);
    k_agg1<<<N_NODES / 4, 256, 0, stream>>>(rowptr, csr_src, xw, norm, gw, h, dd, ds);
    k_agg2z<<<N_NODES / 4, 256, 0, stream>>>(rowptr, csr_src, h, dd, ds, norm,
                                             gb, t2, Wm, noise, z);
    k_outer<<<dim3(N_NODES / 128, N_NODES / 128), 256, 0, stream>>>(z, out);
}